// Round 8
// baseline (399.661 us; speedup 1.0000x reference)
//
#include <hip/hip_runtime.h>
#include <math.h>

#define N_LEVELS 14

typedef __attribute__((ext_vector_type(8))) short bf16x8;
typedef __attribute__((ext_vector_type(4))) float f32x4;

union FragU { unsigned u[4]; bf16x8 v; };

// Preactivations bounded by ~5e-3 -> tanh(x) = x - x^3/3 exact to fp32 here.
__device__ __forceinline__ float tanh_tiny(float x) {
    return x - 0.33333333f * (x * x * x);
}

// Pack two floats as bf16 (rne-ish) into one u32: a -> low, b -> high.
__device__ __forceinline__ unsigned pack_bf16(float a, float b) {
    unsigned ua = (__float_as_uint(a) + 0x8000u) >> 16;
    unsigned ub = (__float_as_uint(b) + 0x8000u) & 0xFFFF0000u;
    return ub | ua;
}

__device__ __forceinline__ unsigned short bf16_of(float a) {
    return (unsigned short)((__float_as_uint(a) + 0x8000u) >> 16);
}

// L1-bypassing 8B load (agent-scope relaxed atomic -> global_load_dwordx2 sc0).
// Rationale (R7 post-mortem): every random table gather misses L1 and pulls a
// full 128B line L2->L1 (model: 56M*128B/256CU/56B-per-cyc ~= 208us ~= measured
// 217us). Bypassing L1 turns each gather into an 8B sub-line L2 return.
__device__ __forceinline__ float2 ld_l1bypass(const float* p) {
    unsigned long long v = __hip_atomic_load((const unsigned long long*)p,
                                             __ATOMIC_RELAXED,
                                             __HIP_MEMORY_SCOPE_AGENT);
    union { unsigned long long u; float2 f; } c;
    c.u = v;
    return c.f;
}

// floor(16 * 1.32^l); indexed by the wave-uniform blockIdx.y -> s_load.
static __device__ const int RES_G[N_LEVELS] =
    {16,21,27,36,48,64,84,111,147,194,256,339,447,590};

// ============================ Kernel A: encode ============================
// One thread = one (point, level); straight-line, 8 independent gathers.
// Concurrency from occupancy (VGPR<=64 -> 8 waves/SIMD). Level-major grid
// keeps ~1 table hot per XCD L2 (R7: FETCH 870->230 MB). This round: gathers
// bypass L1 (sc0) to kill the 128B line-fill per 8B gather.
__global__ __launch_bounds__(256, 8) void encode_kernel(
    const float* __restrict__ x,
    const float* __restrict__ tables,
    const float* __restrict__ bb,
    unsigned* __restrict__ featG,
    int N)
{
    const int l = blockIdx.y;                  // wave-uniform level
    const int n = blockIdx.x * 256 + threadIdx.x;
    if (n >= N) return;

    const float lo0 = bb[0], lo1 = bb[1], lo2 = bb[2];
    const float s0 = bb[3] - lo0, s1 = bb[4] - lo1, s2 = bb[5] - lo2;
    const float xn0 = __fdividef(x[3*n+0] - lo0, s0);
    const float xn1 = __fdividef(x[3*n+1] - lo1, s1);
    const float xn2 = __fdividef(x[3*n+2] - lo2, s2);

    const float r = (float)RES_G[l];
    const float px = xn0*r, py = xn1*r, pz = xn2*r;
    const float bxf = floorf(px), byf = floorf(py), bzf = floorf(pz);
    const float fx = px-bxf, fy = py-byf, fz = pz-bzf;
    const unsigned bx = (unsigned)bxf, by = (unsigned)byf, bz = (unsigned)bzf;
    const unsigned hx0 = bx,               hx1 = bx + 1u;
    const unsigned hy0 = by * 2654435761u, hy1 = (by+1u) * 2654435761u;
    const unsigned hz0 = bz * 805459861u,  hz1 = (bz+1u) * 805459861u;
    const float* tb = tables + ((size_t)l << 20);

    float2 t0 = ld_l1bypass(tb + 2u*((hx0^hy0^hz0)&0x7FFFFu));
    float2 t1 = ld_l1bypass(tb + 2u*((hx0^hy0^hz1)&0x7FFFFu));
    float2 t2 = ld_l1bypass(tb + 2u*((hx0^hy1^hz0)&0x7FFFFu));
    float2 t3 = ld_l1bypass(tb + 2u*((hx0^hy1^hz1)&0x7FFFFu));
    float2 t4 = ld_l1bypass(tb + 2u*((hx1^hy0^hz0)&0x7FFFFu));
    float2 t5 = ld_l1bypass(tb + 2u*((hx1^hy0^hz1)&0x7FFFFu));
    float2 t6 = ld_l1bypass(tb + 2u*((hx1^hy1^hz0)&0x7FFFFu));
    float2 t7 = ld_l1bypass(tb + 2u*((hx1^hy1^hz1)&0x7FFFFu));

    const float wx = fx*fx*(3.0f-2.0f*fx);
    const float wy = fy*fy*(3.0f-2.0f*fy);
    const float wz = fz*fz*(3.0f-2.0f*fz);
    const float wx0 = 1.0f-wx, wy0 = 1.0f-wy, wz0 = 1.0f-wz;

    float f0 = 0.0f, f1 = 0.0f, w;
    w = wx0*wy0*wz0; f0 += w*t0.x; f1 += w*t0.y;
    w = wx0*wy0*wz ; f0 += w*t1.x; f1 += w*t1.y;
    w = wx0*wy *wz0; f0 += w*t2.x; f1 += w*t2.y;
    w = wx0*wy *wz ; f0 += w*t3.x; f1 += w*t3.y;
    w = wx *wy0*wz0; f0 += w*t4.x; f1 += w*t4.y;
    w = wx *wy0*wz ; f0 += w*t5.x; f1 += w*t5.y;
    w = wx *wy *wz0; f0 += w*t6.x; f1 += w*t6.y;
    w = wx *wy *wz ; f0 += w*t7.x; f1 += w*t7.y;

    featG[(size_t)l * (size_t)N + n] = pack_bf16(f0, f1);
}

// ============================ Kernel B: MLP ==============================
// R8: barrier-minimal rewrite. Each wave owns a private LDS region hbuf[wid]
// (features then H1/H2, overwritten in place); wave-local LDS ordering is
// guaranteed by in-order DS + compiler lgkmcnt. The ONLY barrier is after
// the shared weight staging. 68-word rows: A-frag reads land 2 lanes/bank
// (free) instead of 4-way with 64/65.
__global__ __launch_bounds__(256, 4) void mlp_kernel(
    const float* __restrict__ x,
    const float* __restrict__ e,
    const unsigned* __restrict__ featG,
    const float* __restrict__ W1,
    const float* __restrict__ b1,
    const float* __restrict__ W2,
    const float* __restrict__ b2,
    const float* __restrict__ W3,
    const float* __restrict__ b3,
    const float* __restrict__ bb,
    float* __restrict__ out,
    int N)
{
    __shared__ unsigned hbuf[4][32][68];   // per-wave: feat rows 0..17, then H
    __shared__ unsigned w1t[64][21];       // [n][kpair] kp 0..17 real, 18..20 zero
    __shared__ unsigned w2t[64][37];       // [n][kpair] kp 0..31

    const int tid = threadIdx.x;
    const int wid = tid >> 6;
    const int lane = tid & 63;
    const int n0 = blockIdx.x * 256 + tid;
    const int n = (n0 < N) ? n0 : (N - 1);

    // ---- issue feature/e loads first; weight staging overlaps the latency --
    unsigned f[14];
    #pragma unroll
    for (int i = 0; i < 14; ++i)
        f[i] = featG[(size_t)i * (size_t)N + n];
    const float4 e0 = *(const float4*)(e + 8*(size_t)n);
    const float4 e1 = *(const float4*)(e + 8*(size_t)n + 4);

    // ---- weight staging into LDS (bf16 pairs, column-major) ----
    #pragma unroll
    for (int it = 0; it < 5; ++it) {
        int idx = tid + it * 256;              // 0..1279 = 64*20
        int nn = idx / 20, kp = idx % 20;
        unsigned v = 0u;
        if (kp < 18) v = pack_bf16(W1[(2*kp)*64 + nn], W1[(2*kp+1)*64 + nn]);
        w1t[nn][kp] = v;
    }
    #pragma unroll
    for (int it = 0; it < 8; ++it) {
        int idx = tid + it * 256;              // 0..2047 = 64*32
        int nn = idx >> 5, kp = idx & 31;
        w2t[nn][kp] = pack_bf16(W2[(2*kp)*64 + nn], W2[(2*kp+1)*64 + nn]);
    }

    const float lo0 = bb[0], lo1 = bb[1], lo2 = bb[2];
    const float s0 = bb[3] - lo0, s1 = bb[4] - lo1, s2 = bb[5] - lo2;
    const float xn0 = (x[3*n+0] - lo0) / s0;
    const float xn1 = (x[3*n+1] - lo1) / s1;
    const float xn2 = (x[3*n+2] - lo2) / s2;

    __syncthreads();   // weights visible to all waves (ONLY barrier)

    // ---- per-wave feature write (wave-private region, no barrier) ----
    unsigned (*hw)[68] = hbuf[wid];
    #pragma unroll
    for (int i = 0; i < 14; ++i) hw[i][lane] = f[i];
    hw[14][lane] = pack_bf16(e0.x, e0.y);
    hw[15][lane] = pack_bf16(e0.z, e0.w);
    hw[16][lane] = pack_bf16(e1.x, e1.y);
    hw[17][lane] = pack_bf16(e1.z, e1.w);

    const int c = lane & 15;       // A row(point) / D col(unit) within tile
    const int q = lane >> 4;       // k-quad

    f32x4 acc[4][4];
    #pragma unroll
    for (int mt = 0; mt < 4; ++mt)
        #pragma unroll
        for (int nt = 0; nt < 4; ++nt)
            acc[mt][nt] = (f32x4)(0.0f);

    // ---- Layer 1: K=64 logical (36 real, rest zeroed in regs) ----
    #pragma unroll
    for (int mt = 0; mt < 4; ++mt) {
        const int pA = mt * 16 + c;
        FragU A0, A1;
        #pragma unroll
        for (int w = 0; w < 4; ++w) A0.u[w] = hw[q*4 + w][pA];
        {
            unsigned r16 = hw[16][pA], r17 = hw[17][pA];
            A1.u[0] = (q == 0) ? r16 : 0u;
            A1.u[1] = (q == 0) ? r17 : 0u;
            A1.u[2] = 0u; A1.u[3] = 0u;
        }
        #pragma unroll
        for (int nt = 0; nt < 4; ++nt) {
            const int bn = nt * 16 + c;
            FragU B0, B1;
            #pragma unroll
            for (int w = 0; w < 4; ++w) B0.u[w] = w1t[bn][4*q + w];
            #pragma unroll
            for (int w = 0; w < 4; ++w) {
                unsigned bv = w1t[bn][(q == 0) ? (16 + w) : 0];
                B1.u[w] = (q == 0) ? bv : 0u;
            }
            acc[mt][nt] = __builtin_amdgcn_mfma_f32_16x16x32_bf16(A0.v, B0.v, acc[mt][nt], 0, 0, 0);
            acc[mt][nt] = __builtin_amdgcn_mfma_f32_16x16x32_bf16(A1.v, B1.v, acc[mt][nt], 0, 0, 0);
        }
    }

    // bias + tanh + write H1 bf16 into hw rows 0..31 (A-frag layout).
    // Same-wave DS ops execute in order -> reads above complete before these
    // writes overwrite the feature rows; no barrier needed.
    {
        unsigned short* hb = (unsigned short*)&hw[0][0];
        #pragma unroll
        for (int nt = 0; nt < 4; ++nt) {
            const int u = nt * 16 + c;
            const float bias = b1[u];
            unsigned short* hrow = hb + (u >> 1) * (68 * 2) + (u & 1);
            #pragma unroll
            for (int mt = 0; mt < 4; ++mt) {
                #pragma unroll
                for (int r = 0; r < 4; ++r) {
                    float h = tanh_tiny(acc[mt][nt][r] + bias);
                    int p = mt * 16 + q * 4 + r;
                    hrow[p * 2] = bf16_of(h);
                }
            }
        }
    }

    // ---- Layer 2: K=64, all rows real ----
    #pragma unroll
    for (int mt = 0; mt < 4; ++mt)
        #pragma unroll
        for (int nt = 0; nt < 4; ++nt)
            acc[mt][nt] = (f32x4)(0.0f);

    #pragma unroll
    for (int mt = 0; mt < 4; ++mt) {
        const int pA = mt * 16 + c;
        FragU A0, A1;
        #pragma unroll
        for (int w = 0; w < 4; ++w) A0.u[w] = hw[q*4 + w][pA];
        #pragma unroll
        for (int w = 0; w < 4; ++w) A1.u[w] = hw[16 + q*4 + w][pA];
        #pragma unroll
        for (int nt = 0; nt < 4; ++nt) {
            const int bn = nt * 16 + c;
            FragU B0, B1;
            #pragma unroll
            for (int w = 0; w < 4; ++w) B0.u[w] = w2t[bn][4*q + w];
            #pragma unroll
            for (int w = 0; w < 4; ++w) B1.u[w] = w2t[bn][16 + 4*q + w];
            acc[mt][nt] = __builtin_amdgcn_mfma_f32_16x16x32_bf16(A0.v, B0.v, acc[mt][nt], 0, 0, 0);
            acc[mt][nt] = __builtin_amdgcn_mfma_f32_16x16x32_bf16(A1.v, B1.v, acc[mt][nt], 0, 0, 0);
        }
    }

    // bias + tanh + write H2 (same layout, same in-order argument)
    {
        unsigned short* hb = (unsigned short*)&hw[0][0];
        #pragma unroll
        for (int nt = 0; nt < 4; ++nt) {
            const int u = nt * 16 + c;
            const float bias = b2[u];
            unsigned short* hrow = hb + (u >> 1) * (68 * 2) + (u & 1);
            #pragma unroll
            for (int mt = 0; mt < 4; ++mt) {
                #pragma unroll
                for (int r = 0; r < 4; ++r) {
                    float h = tanh_tiny(acc[mt][nt][r] + bias);
                    int p = mt * 16 + q * 4 + r;
                    hrow[p * 2] = bf16_of(h);
                }
            }
        }
    }

    // ---- Layer 3: 64 -> 3, per-thread VALU (W3 uniform -> s_load) ----
    float o0 = b3[0], o1 = b3[1], o2 = b3[2];
    #pragma unroll
    for (int kp = 0; kp < 32; ++kp) {
        unsigned pw = hw[kp][lane];
        float f0 = __uint_as_float(pw << 16);
        float f1 = __uint_as_float(pw & 0xFFFF0000u);
        o0 += f0 * W3[(2*kp)*3 + 0] + f1 * W3[(2*kp+1)*3 + 0];
        o1 += f0 * W3[(2*kp)*3 + 1] + f1 * W3[(2*kp+1)*3 + 1];
        o2 += f0 * W3[(2*kp)*3 + 2] + f1 * W3[(2*kp+1)*3 + 2];
    }

    if (n0 < N) {
        out[3*n+0] = (o0 + xn0) * s0 + lo0;
        out[3*n+1] = (o1 + xn1) * s1 + lo1;
        out[3*n+2] = (o2 + xn2) * s2 + lo2;
    }
}

extern "C" void kernel_launch(void* const* d_in, const int* in_sizes, int n_in,
                              void* d_out, int out_size, void* d_ws, size_t ws_size,
                              hipStream_t stream) {
    const float* x      = (const float*)d_in[0];
    const float* e      = (const float*)d_in[1];
    const float* tables = (const float*)d_in[2];
    const float* W1     = (const float*)d_in[3];
    const float* b1     = (const float*)d_in[4];
    const float* W2     = (const float*)d_in[5];
    const float* b2     = (const float*)d_in[6];
    const float* W3     = (const float*)d_in[7];
    const float* b3     = (const float*)d_in[8];
    const float* bb     = (const float*)d_in[9];
    float* out = (float*)d_out;
    unsigned* featG = (unsigned*)d_ws;   // 14 * N u32 = 28 MB

    const int N = in_sizes[0] / 3;
    const int nblk = (N + 255) / 256;
    dim3 egrid(nblk, N_LEVELS);
    encode_kernel<<<egrid, 256, 0, stream>>>(x, tables, bb, featG, N);
    mlp_kernel<<<nblk, 256, 0, stream>>>(x, e, featG, W1, b1, W2, b2,
                                         W3, b3, bb, out, N);
}

// Round 9
// 333.940 us; speedup vs baseline: 1.1968x; 1.1968x over previous
//
#include <hip/hip_runtime.h>
#include <math.h>

#define N_LEVELS 14

typedef __attribute__((ext_vector_type(8))) short bf16x8;
typedef __attribute__((ext_vector_type(4))) float f32x4;

union FragU { unsigned u[4]; bf16x8 v; };

// Preactivations bounded by ~5e-3 -> tanh(x) = x - x^3/3 exact to fp32 here.
__device__ __forceinline__ float tanh_tiny(float x) {
    return x - 0.33333333f * (x * x * x);
}

__device__ __forceinline__ unsigned pack_bf16(float a, float b) {
    unsigned ua = (__float_as_uint(a) + 0x8000u) >> 16;
    unsigned ub = (__float_as_uint(b) + 0x8000u) & 0xFFFF0000u;
    return ub | ua;
}

__device__ __forceinline__ unsigned short bf16_of(float a) {
    return (unsigned short)((__float_as_uint(a) + 0x8000u) >> 16);
}

// 5-bit -> every-3rd-bit spread (Morton).
__device__ __forceinline__ unsigned part1by2(unsigned v) {
    v &= 0x3FFu;
    v = (v | (v << 16)) & 0x30000FFu;
    v = (v | (v << 8))  & 0x300F00Fu;
    v = (v | (v << 4))  & 0x30C30C3u;
    v = (v | (v << 2))  & 0x9249249u;
    return v;
}

static __device__ const int RES_G[N_LEVELS] =
    {16,21,27,36,48,64,84,111,147,194,256,339,447,590};

// ===================== sort pipeline (counting sort by Morton-32^3) ========
__global__ __launch_bounds__(256) void zero_hist_kernel(unsigned* __restrict__ hist) {
    hist[blockIdx.x * 256 + threadIdx.x] = 0u;   // grid = 128 blocks = 32768
}

__global__ __launch_bounds__(256) void hist_kernel(
    const float* __restrict__ x, const float* __restrict__ bb,
    unsigned* __restrict__ binid, unsigned* __restrict__ hist, int N)
{
    const int n = blockIdx.x * 256 + threadIdx.x;
    if (n >= N) return;
    const float lo0 = bb[0], lo1 = bb[1], lo2 = bb[2];
    const float s0 = bb[3] - lo0, s1 = bb[4] - lo1, s2 = bb[5] - lo2;
    const float xn0 = __fdividef(x[3*n+0] - lo0, s0);
    const float xn1 = __fdividef(x[3*n+1] - lo1, s1);
    const float xn2 = __fdividef(x[3*n+2] - lo2, s2);
    unsigned cx = min(31, (int)(xn0 * 32.0f));
    unsigned cy = min(31, (int)(xn1 * 32.0f));
    unsigned cz = min(31, (int)(xn2 * 32.0f));
    unsigned m = part1by2(cx) | (part1by2(cy) << 1) | (part1by2(cz) << 2);
    binid[n] = m;
    atomicAdd(&hist[m], 1u);
}

// One block, 1024 threads, 32 bins/thread: hist -> exclusive start offsets.
__global__ __launch_bounds__(1024) void scan_kernel(unsigned* __restrict__ hist) {
    __shared__ unsigned ps[1024];
    const int t = threadIdx.x;
    unsigned loc[32];
    unsigned s = 0;
    #pragma unroll
    for (int j = 0; j < 32; ++j) { loc[j] = hist[t*32 + j]; s += loc[j]; }
    ps[t] = s;
    __syncthreads();
    // Hillis-Steele inclusive scan over 1024 partials
    for (int off = 1; off < 1024; off <<= 1) {
        unsigned v = (t >= off) ? ps[t - off] : 0u;
        __syncthreads();
        ps[t] += v;
        __syncthreads();
    }
    unsigned run = ps[t] - s;   // exclusive prefix for this thread's chunk
    #pragma unroll
    for (int j = 0; j < 32; ++j) { hist[t*32 + j] = run; run += loc[j]; }
}

__global__ __launch_bounds__(256) void scatter_kernel(
    const float* __restrict__ x, const unsigned* __restrict__ binid,
    unsigned* __restrict__ hist, unsigned* __restrict__ perm,
    float* __restrict__ xs, int N)
{
    const int n = blockIdx.x * 256 + threadIdx.x;
    if (n >= N) return;
    unsigned pos = atomicAdd(&hist[binid[n]], 1u);
    perm[pos] = (unsigned)n;
    xs[3*pos+0] = x[3*n+0];
    xs[3*pos+1] = x[3*n+1];
    xs[3*pos+2] = x[3*n+2];
}

// Pack W1/W2 once into bf16-pair images -> MLP staging becomes coalesced.
__global__ __launch_bounds__(256) void pack_w_kernel(
    const float* __restrict__ W1, const float* __restrict__ W2,
    unsigned* __restrict__ w1p, unsigned* __restrict__ w2p)
{
    const int tid = threadIdx.x;
    #pragma unroll
    for (int it = 0; it < 6; ++it) {
        int idx = tid + it * 256;                  // 64*21 = 1344
        if (idx < 1344) {
            int nn = idx / 21, kp = idx % 21;
            unsigned v = 0u;
            if (kp < 18) v = pack_bf16(W1[(2*kp)*64 + nn], W1[(2*kp+1)*64 + nn]);
            w1p[idx] = v;
        }
    }
    #pragma unroll
    for (int it = 0; it < 10; ++it) {
        int idx = tid + it * 256;                  // 64*37 = 2368
        if (idx < 2368) {
            int nn = idx / 37, kp = idx % 37;
            unsigned v = 0u;
            if (kp < 32) v = pack_bf16(W2[(2*kp)*64 + nn], W2[(2*kp+1)*64 + nn]);
            w2p[idx] = v;
        }
    }
}

// ============================ Kernel A: encode ============================
// One thread = one (sorted point, level). Sorted (Morton) order: a wave's 64
// points sit in a ~0.05-side cube -> coarse/mid-level corner gathers collapse
// onto few table lines (TA merging + L1 hits) -> attacks the divergent-miss
// throughput wall directly (R6-R8: ~0.42 req/cyc/CU regardless of occupancy).
__global__ __launch_bounds__(256, 8) void encode_kernel(
    const float* __restrict__ xs,
    const float* __restrict__ tables,
    const float* __restrict__ bb,
    unsigned* __restrict__ featG,
    int N)
{
    const int l = blockIdx.y;
    const int i = blockIdx.x * 256 + threadIdx.x;   // sorted index
    if (i >= N) return;

    const float lo0 = bb[0], lo1 = bb[1], lo2 = bb[2];
    const float s0 = bb[3] - lo0, s1 = bb[4] - lo1, s2 = bb[5] - lo2;
    const float xn0 = __fdividef(xs[3*i+0] - lo0, s0);
    const float xn1 = __fdividef(xs[3*i+1] - lo1, s1);
    const float xn2 = __fdividef(xs[3*i+2] - lo2, s2);

    const float r = (float)RES_G[l];
    const float px = xn0*r, py = xn1*r, pz = xn2*r;
    const float bxf = floorf(px), byf = floorf(py), bzf = floorf(pz);
    const float fx = px-bxf, fy = py-byf, fz = pz-bzf;
    const unsigned bx = (unsigned)bxf, by = (unsigned)byf, bz = (unsigned)bzf;
    const unsigned hx0 = bx,               hx1 = bx + 1u;
    const unsigned hy0 = by * 2654435761u, hy1 = (by+1u) * 2654435761u;
    const unsigned hz0 = bz * 805459861u,  hz1 = (bz+1u) * 805459861u;
    const float* tb = tables + ((size_t)l << 20);

    float2 t0 = *(const float2*)(tb + 2u*((hx0^hy0^hz0)&0x7FFFFu));
    float2 t1 = *(const float2*)(tb + 2u*((hx0^hy0^hz1)&0x7FFFFu));
    float2 t2 = *(const float2*)(tb + 2u*((hx0^hy1^hz0)&0x7FFFFu));
    float2 t3 = *(const float2*)(tb + 2u*((hx0^hy1^hz1)&0x7FFFFu));
    float2 t4 = *(const float2*)(tb + 2u*((hx1^hy0^hz0)&0x7FFFFu));
    float2 t5 = *(const float2*)(tb + 2u*((hx1^hy0^hz1)&0x7FFFFu));
    float2 t6 = *(const float2*)(tb + 2u*((hx1^hy1^hz0)&0x7FFFFu));
    float2 t7 = *(const float2*)(tb + 2u*((hx1^hy1^hz1)&0x7FFFFu));

    const float wx = fx*fx*(3.0f-2.0f*fx);
    const float wy = fy*fy*(3.0f-2.0f*fy);
    const float wz = fz*fz*(3.0f-2.0f*fz);
    const float wx0 = 1.0f-wx, wy0 = 1.0f-wy, wz0 = 1.0f-wz;

    float f0 = 0.0f, f1 = 0.0f, w;
    w = wx0*wy0*wz0; f0 += w*t0.x; f1 += w*t0.y;
    w = wx0*wy0*wz ; f0 += w*t1.x; f1 += w*t1.y;
    w = wx0*wy *wz0; f0 += w*t2.x; f1 += w*t2.y;
    w = wx0*wy *wz ; f0 += w*t3.x; f1 += w*t3.y;
    w = wx *wy0*wz0; f0 += w*t4.x; f1 += w*t4.y;
    w = wx *wy0*wz ; f0 += w*t5.x; f1 += w*t5.y;
    w = wx *wy *wz0; f0 += w*t6.x; f1 += w*t6.y;
    w = wx *wy *wz ; f0 += w*t7.x; f1 += w*t7.y;

    featG[(size_t)l * (size_t)N + i] = pack_bf16(f0, f1);
}

// ============================ Kernel B: MLP ==============================
// R7's proven-exact structure (block-shared fbuf, barriers). Changes: packed
// coalesced weight staging (w1p/w2p images), sorted-space inputs (featG/xs
// coalesced, e gathered via perm), scattered out writes.
__global__ __launch_bounds__(256, 4) void mlp_kernel(
    const float* __restrict__ xs,
    const float* __restrict__ e,
    const unsigned* __restrict__ perm,
    const unsigned* __restrict__ featG,
    const unsigned* __restrict__ w1p,
    const unsigned* __restrict__ w2p,
    const float* __restrict__ b1,
    const float* __restrict__ b2,
    const float* __restrict__ W3,
    const float* __restrict__ b3,
    const float* __restrict__ bb,
    float* __restrict__ out,
    int N)
{
    __shared__ unsigned fbuf[32][257];   // feat(18) / H1(32) / H2(32)
    __shared__ unsigned w1t[64][21];
    __shared__ unsigned w2t[64][37];

    const int tid = threadIdx.x;
    const int i0 = blockIdx.x * 256 + tid;           // sorted index
    const int i = (i0 < N) ? i0 : (N - 1);
    const unsigned n = perm[i];                      // original index

    // issue long-latency loads first
    unsigned f[14];
    #pragma unroll
    for (int k = 0; k < 14; ++k)
        f[k] = featG[(size_t)k * (size_t)N + i];
    const float4 e0 = *(const float4*)(e + 8*(size_t)n);
    const float4 e1 = *(const float4*)(e + 8*(size_t)n + 4);

    // coalesced packed-weight staging
    {
        unsigned* w1f = &w1t[0][0];
        #pragma unroll
        for (int it = 0; it < 6; ++it) {
            int idx = tid + it * 256;
            if (idx < 1344) w1f[idx] = w1p[idx];
        }
        unsigned* w2f = &w2t[0][0];
        #pragma unroll
        for (int it = 0; it < 10; ++it) {
            int idx = tid + it * 256;
            if (idx < 2368) w2f[idx] = w2p[idx];
        }
    }

    const float lo0 = bb[0], lo1 = bb[1], lo2 = bb[2];
    const float s0 = bb[3] - lo0, s1 = bb[4] - lo1, s2 = bb[5] - lo2;
    const float xn0 = (xs[3*i+0] - lo0) / s0;
    const float xn1 = (xs[3*i+1] - lo1) / s1;
    const float xn2 = (xs[3*i+2] - lo2) / s2;

    #pragma unroll
    for (int k = 0; k < 14; ++k) fbuf[k][tid] = f[k];
    fbuf[14][tid] = pack_bf16(e0.x, e0.y);
    fbuf[15][tid] = pack_bf16(e0.z, e0.w);
    fbuf[16][tid] = pack_bf16(e1.x, e1.y);
    fbuf[17][tid] = pack_bf16(e1.z, e1.w);

    __syncthreads();

    const int wid = tid >> 6;
    const int lane = tid & 63;
    const int c = lane & 15;
    const int q = lane >> 4;
    const int pbase = wid * 64;

    f32x4 acc[4][4];
    #pragma unroll
    for (int mt = 0; mt < 4; ++mt)
        #pragma unroll
        for (int nt = 0; nt < 4; ++nt)
            acc[mt][nt] = (f32x4)(0.0f);

    // ---- Layer 1 ----
    #pragma unroll
    for (int mt = 0; mt < 4; ++mt) {
        const int pA = pbase + mt * 16 + c;
        FragU A0, A1;
        #pragma unroll
        for (int w = 0; w < 4; ++w) A0.u[w] = fbuf[q*4 + w][pA];
        {
            unsigned r16 = fbuf[16][pA], r17 = fbuf[17][pA];
            A1.u[0] = (q == 0) ? r16 : 0u;
            A1.u[1] = (q == 0) ? r17 : 0u;
            A1.u[2] = 0u; A1.u[3] = 0u;
        }
        #pragma unroll
        for (int nt = 0; nt < 4; ++nt) {
            const int bn = nt * 16 + c;
            FragU B0, B1;
            #pragma unroll
            for (int w = 0; w < 4; ++w) B0.u[w] = w1t[bn][4*q + w];
            #pragma unroll
            for (int w = 0; w < 4; ++w) {
                unsigned bv = w1t[bn][(q == 0) ? (16 + w) : 0];
                B1.u[w] = (q == 0) ? bv : 0u;
            }
            acc[mt][nt] = __builtin_amdgcn_mfma_f32_16x16x32_bf16(A0.v, B0.v, acc[mt][nt], 0, 0, 0);
            acc[mt][nt] = __builtin_amdgcn_mfma_f32_16x16x32_bf16(A1.v, B1.v, acc[mt][nt], 0, 0, 0);
        }
    }

    __syncthreads();

    {
        unsigned short* hbase = (unsigned short*)&fbuf[0][0];
        #pragma unroll
        for (int nt = 0; nt < 4; ++nt) {
            const int u = nt * 16 + c;
            const float bias = b1[u];
            unsigned short* hrow = hbase + (u >> 1) * (257 * 2) + (u & 1);
            #pragma unroll
            for (int mt = 0; mt < 4; ++mt) {
                #pragma unroll
                for (int r = 0; r < 4; ++r) {
                    float h = tanh_tiny(acc[mt][nt][r] + bias);
                    int p = pbase + mt * 16 + q * 4 + r;
                    hrow[p * 2] = bf16_of(h);
                }
            }
        }
    }

    __syncthreads();

    // ---- Layer 2 ----
    #pragma unroll
    for (int mt = 0; mt < 4; ++mt)
        #pragma unroll
        for (int nt = 0; nt < 4; ++nt)
            acc[mt][nt] = (f32x4)(0.0f);

    #pragma unroll
    for (int mt = 0; mt < 4; ++mt) {
        const int pA = pbase + mt * 16 + c;
        FragU A0, A1;
        #pragma unroll
        for (int w = 0; w < 4; ++w) A0.u[w] = fbuf[q*4 + w][pA];
        #pragma unroll
        for (int w = 0; w < 4; ++w) A1.u[w] = fbuf[16 + q*4 + w][pA];
        #pragma unroll
        for (int nt = 0; nt < 4; ++nt) {
            const int bn = nt * 16 + c;
            FragU B0, B1;
            #pragma unroll
            for (int w = 0; w < 4; ++w) B0.u[w] = w2t[bn][4*q + w];
            #pragma unroll
            for (int w = 0; w < 4; ++w) B1.u[w] = w2t[bn][16 + 4*q + w];
            acc[mt][nt] = __builtin_amdgcn_mfma_f32_16x16x32_bf16(A0.v, B0.v, acc[mt][nt], 0, 0, 0);
            acc[mt][nt] = __builtin_amdgcn_mfma_f32_16x16x32_bf16(A1.v, B1.v, acc[mt][nt], 0, 0, 0);
        }
    }

    __syncthreads();

    {
        unsigned short* hbase = (unsigned short*)&fbuf[0][0];
        #pragma unroll
        for (int nt = 0; nt < 4; ++nt) {
            const int u = nt * 16 + c;
            const float bias = b2[u];
            unsigned short* hrow = hbase + (u >> 1) * (257 * 2) + (u & 1);
            #pragma unroll
            for (int mt = 0; mt < 4; ++mt) {
                #pragma unroll
                for (int r = 0; r < 4; ++r) {
                    float h = tanh_tiny(acc[mt][nt][r] + bias);
                    int p = pbase + mt * 16 + q * 4 + r;
                    hrow[p * 2] = bf16_of(h);
                }
            }
        }
    }

    __syncthreads();

    // ---- Layer 3 ----
    float o0 = b3[0], o1 = b3[1], o2 = b3[2];
    #pragma unroll
    for (int kp = 0; kp < 32; ++kp) {
        unsigned pw = fbuf[kp][tid];
        float f0 = __uint_as_float(pw << 16);
        float f1 = __uint_as_float(pw & 0xFFFF0000u);
        o0 += f0 * W3[(2*kp)*3 + 0] + f1 * W3[(2*kp+1)*3 + 0];
        o1 += f0 * W3[(2*kp)*3 + 1] + f1 * W3[(2*kp+1)*3 + 1];
        o2 += f0 * W3[(2*kp)*3 + 2] + f1 * W3[(2*kp+1)*3 + 2];
    }

    if (i0 < N) {
        out[3*n+0] = (o0 + xn0) * s0 + lo0;
        out[3*n+1] = (o1 + xn1) * s1 + lo1;
        out[3*n+2] = (o2 + xn2) * s2 + lo2;
    }
}

extern "C" void kernel_launch(void* const* d_in, const int* in_sizes, int n_in,
                              void* d_out, int out_size, void* d_ws, size_t ws_size,
                              hipStream_t stream) {
    const float* x      = (const float*)d_in[0];
    const float* e      = (const float*)d_in[1];
    const float* tables = (const float*)d_in[2];
    const float* W1     = (const float*)d_in[3];
    const float* b1     = (const float*)d_in[4];
    const float* W2     = (const float*)d_in[5];
    const float* b2     = (const float*)d_in[6];
    const float* W3     = (const float*)d_in[7];
    const float* b3     = (const float*)d_in[8];
    const float* bb     = (const float*)d_in[9];
    float* out = (float*)d_out;

    const int N = in_sizes[0] / 3;
    // ws layout (u32 units): featG 14N | perm N | binid N | xs 3N(float) |
    // hist 32768 | w1p 1344 | w2p 2368   -- total ~= 19N + 36k u32 ~= 38.2 MB
    unsigned* ws   = (unsigned*)d_ws;
    unsigned* featG = ws;
    unsigned* perm  = ws + (size_t)14 * N;
    unsigned* binid = ws + (size_t)15 * N;
    float*    xs    = (float*)(ws + (size_t)16 * N);
    unsigned* hist  = ws + (size_t)19 * N;
    unsigned* w1p   = hist + 32768;
    unsigned* w2p   = w1p + 1344;

    const int nblk = (N + 255) / 256;

    zero_hist_kernel<<<128, 256, 0, stream>>>(hist);
    pack_w_kernel<<<1, 256, 0, stream>>>(W1, W2, w1p, w2p);
    hist_kernel<<<nblk, 256, 0, stream>>>(x, bb, binid, hist, N);
    scan_kernel<<<1, 1024, 0, stream>>>(hist);
    scatter_kernel<<<nblk, 256, 0, stream>>>(x, binid, hist, perm, xs, N);
    dim3 egrid(nblk, N_LEVELS);
    encode_kernel<<<egrid, 256, 0, stream>>>(xs, tables, bb, featG, N);
    mlp_kernel<<<nblk, 256, 0, stream>>>(xs, e, perm, featG, w1p, w2p,
                                         b1, b2, W3, b3, bb, out, N);
}